// Round 1
// baseline (66.740 us; speedup 1.0000x reference)
//
#include <hip/hip_runtime.h>
#include <math.h>

// Problem constants
#define B_   32
#define N_   64
#define D_   256
#define E_   32
#define DN_  64
#define H_   8
#define M_   32
#define HM_  256      // H_*M_
#define BN_  2048     // B_*N_
#define EPS_ 1e-5f
#define INV_SQRT2 0.70710678118654752f

// ---------------------------------------------------------------------------
// Kernel 0: mask normalization. Reference mask is bool; harness may ship it
// as int32 or raw 1-byte bools. Detect by scanning the first 2048 bytes read
// as int32: any value with bits outside {0,1} => byte format. Write a float
// mask (0.0/1.0) of length BN_ into workspace.
// 1 block x 512 threads. Detection reads only the first 2048 bytes (safe in
// both formats).
// ---------------------------------------------------------------------------
__global__ __launch_bounds__(512) void mask_convert(const int* __restrict__ mraw,
                                                    float* __restrict__ mf) {
    __shared__ int s_flag;
    const int t = threadIdx.x;
    if (t == 0) s_flag = 0;
    __syncthreads();
    int v = mraw[t];                 // 512 ints = first 2048 bytes
    if ((v & ~1) != 0) atomicOr(&s_flag, 1);
    __syncthreads();
    const bool bytefmt = (s_flag != 0);
    const unsigned char* mb = (const unsigned char*)mraw;
    #pragma unroll
    for (int k = t; k < BN_; k += 512) {
        float val = bytefmt ? (mb[k] != 0 ? 1.0f : 0.0f)
                            : (mraw[k] != 0 ? 1.0f : 0.0f);
        mf[k] = val;
    }
}

// ---------------------------------------------------------------------------
// Kernel 1: node precompute.
//   emb_ln = LN(embeddings) * mask
//   recv = (emb_ln @ W_recv) / sqrt2        [BN_, HM_]
//   send = (emb_ln @ W_send) / sqrt2
//   rn   = (node_features @ W_recv_node) / sqrt2   (pre-scaled for sigmoid)
//   sn   = (node_features @ W_send_node) / sqrt2
// One block handles G=4 nodes (512 blocks x 256 threads); W columns are read
// once per block (L2-resident), emb rows staged in LDS.
// ---------------------------------------------------------------------------
#define G_ 4
__global__ __launch_bounds__(256) void node_pre(
        const float* __restrict__ emb, const float* __restrict__ nfeat,
        const float* __restrict__ mf,
        const float* __restrict__ Wr, const float* __restrict__ Ws,
        const float* __restrict__ Wrn, const float* __restrict__ Wsn,
        float* __restrict__ g_recv, float* __restrict__ g_send,
        float* __restrict__ g_rn, float* __restrict__ g_sn) {
    __shared__ __align__(16) float ln_s[G_][D_];
    __shared__ __align__(16) float nf_s[G_][DN_];
    __shared__ float rsum[4], rsum2[4];

    const int t = threadIdx.x;
    const int wid = t >> 6;
    const int g0 = blockIdx.x * G_;

    // --- LayerNorm each of the G rows, stage into LDS ---
    for (int g = 0; g < G_; ++g) {
        const int bn = g0 + g;
        float x = emb[bn * D_ + t];
        float s = x, s2 = x * x;
        #pragma unroll
        for (int k = 32; k >= 1; k >>= 1) {
            s  += __shfl_xor(s, k);
            s2 += __shfl_xor(s2, k);
        }
        if ((t & 63) == 0) { rsum[wid] = s; rsum2[wid] = s2; }
        __syncthreads();
        float S  = rsum[0] + rsum[1] + rsum[2] + rsum[3];
        float S2 = rsum2[0] + rsum2[1] + rsum2[2] + rsum2[3];
        float mu  = S * (1.0f / D_);
        float var = S2 * (1.0f / D_) - mu * mu;
        float mfv = mf[bn];
        ln_s[g][t] = (x - mu) * rsqrtf(var + EPS_) * mfv;
        if (t < DN_) nf_s[g][t] = nfeat[bn * DN_ + t];
        __syncthreads();
    }

    // --- 4 matvecs; thread t owns output channel t ---
    float ar[G_] = {0,0,0,0}, asd[G_] = {0,0,0,0};
    float arn[G_] = {0,0,0,0}, asn[G_] = {0,0,0,0};

    for (int dd = 0; dd < D_; dd += 4) {
        float wr0 = Wr[(dd+0)*HM_ + t], wr1 = Wr[(dd+1)*HM_ + t];
        float wr2 = Wr[(dd+2)*HM_ + t], wr3 = Wr[(dd+3)*HM_ + t];
        float ws0 = Ws[(dd+0)*HM_ + t], ws1 = Ws[(dd+1)*HM_ + t];
        float ws2 = Ws[(dd+2)*HM_ + t], ws3 = Ws[(dd+3)*HM_ + t];
        #pragma unroll
        for (int g = 0; g < G_; ++g) {
            float4 e = *(const float4*)&ln_s[g][dd];
            ar[g]  = fmaf(e.x, wr0, fmaf(e.y, wr1, fmaf(e.z, wr2, fmaf(e.w, wr3, ar[g]))));
            asd[g] = fmaf(e.x, ws0, fmaf(e.y, ws1, fmaf(e.z, ws2, fmaf(e.w, ws3, asd[g]))));
        }
    }
    for (int dd = 0; dd < DN_; dd += 4) {
        float wr0 = Wrn[(dd+0)*HM_ + t], wr1 = Wrn[(dd+1)*HM_ + t];
        float wr2 = Wrn[(dd+2)*HM_ + t], wr3 = Wrn[(dd+3)*HM_ + t];
        float ws0 = Wsn[(dd+0)*HM_ + t], ws1 = Wsn[(dd+1)*HM_ + t];
        float ws2 = Wsn[(dd+2)*HM_ + t], ws3 = Wsn[(dd+3)*HM_ + t];
        #pragma unroll
        for (int g = 0; g < G_; ++g) {
            float4 e = *(const float4*)&nf_s[g][dd];
            arn[g] = fmaf(e.x, wr0, fmaf(e.y, wr1, fmaf(e.z, wr2, fmaf(e.w, wr3, arn[g]))));
            asn[g] = fmaf(e.x, ws0, fmaf(e.y, ws1, fmaf(e.z, ws2, fmaf(e.w, ws3, asn[g]))));
        }
    }

    #pragma unroll
    for (int g = 0; g < G_; ++g) {
        const int bn = g0 + g;
        g_recv[bn * HM_ + t] = ar[g]  * INV_SQRT2;
        g_send[bn * HM_ + t] = asd[g] * INV_SQRT2;
        g_rn[bn * HM_ + t]   = arn[g] * INV_SQRT2;
        g_sn[bn * HM_ + t]   = asn[g] * INV_SQRT2;
    }
}

// ---------------------------------------------------------------------------
// Kernel 2: edge aggregation + final per-head LayerNorm.
// One block per receiver (b,j), 256 threads (thread t = channel hm).
//   acc[t] = sum_i mask_i * tanh(recv_j+send_i) * sigmoid(rn_j+sn_i)
//                 * (ef[b,i,j,:] . W_edge[:,t])
// ef[b,i,j,e] is block-uniform -> scalar loads. Final LN over each head's 32
// channels via __shfl_xor within 32-lane groups.
// ---------------------------------------------------------------------------
__global__ __launch_bounds__(256) void edge_agg(
        const float* __restrict__ edge, const float* __restrict__ mf,
        const float* __restrict__ We,
        const float* __restrict__ g_recv, const float* __restrict__ g_send,
        const float* __restrict__ g_rn, const float* __restrict__ g_sn,
        float* __restrict__ out) {
    const int t  = threadIdx.x;
    const int bn = blockIdx.x;        // receiver flat index
    const int b  = bn >> 6;
    const int j  = bn & 63;

    // wave-uniform sender mask bits (all waves compute the same value)
    unsigned long long mbits = __ballot(mf[b * N_ + (t & 63)] > 0.5f);

    float acc = 0.0f;
    if (mf[bn] > 0.5f) {
        const float recv_j = g_recv[bn * HM_ + t];
        const float rn_j   = g_rn[bn * HM_ + t];
        float we[E_];
        #pragma unroll
        for (int e = 0; e < E_; ++e) we[e] = We[e * HM_ + t];

        const float* efb = edge + (b * N_ * N_ + j) * E_;   // + i*N_*E_
        for (int i = 0; i < N_; ++i) {
            if ((mbits >> i) & 1ull) {
                const float* ef = efb + i * (N_ * E_);      // block-uniform
                float ep = 0.0f;
                #pragma unroll
                for (int e4 = 0; e4 < E_ / 4; ++e4) {
                    float4 ev = *(const float4*)(ef + 4 * e4);
                    ep = fmaf(ev.x, we[4*e4+0], ep);
                    ep = fmaf(ev.y, we[4*e4+1], ep);
                    ep = fmaf(ev.z, we[4*e4+2], ep);
                    ep = fmaf(ev.w, we[4*e4+3], ep);
                }
                const int sid = b * N_ + i;
                float si  = g_send[sid * HM_ + t];
                float sni = g_sn[sid * HM_ + t];
                // tanh(x) = 1 - 2/(e^{2x}+1)
                float tx = recv_j + si;
                float th = 1.0f - 2.0f / (__expf(2.0f * tx) + 1.0f);
                float z  = rn_j + sni;                       // already /sqrt2
                float sg = 1.0f / (1.0f + __expf(-z));
                acc = fmaf(th * sg, ep, acc);
            }
        }
    }

    // Final LN over M_=32 channels per head (32-lane groups within the wave)
    float s = acc, s2 = acc * acc;
    #pragma unroll
    for (int k = 16; k >= 1; k >>= 1) {
        s  += __shfl_xor(s, k);
        s2 += __shfl_xor(s2, k);
    }
    float mu  = s * (1.0f / M_);
    float var = s2 * (1.0f / M_) - mu * mu;
    out[bn * HM_ + t] = (acc - mu) * rsqrtf(var + EPS_);
}

// ---------------------------------------------------------------------------
extern "C" void kernel_launch(void* const* d_in, const int* in_sizes, int n_in,
                              void* d_out, int out_size, void* d_ws, size_t ws_size,
                              hipStream_t stream) {
    const float* embeddings = (const float*)d_in[0];
    const float* edge_feat  = (const float*)d_in[1];
    const int*   mask_raw   = (const int*)d_in[2];
    const float* node_feat  = (const float*)d_in[3];
    const float* W_edge     = (const float*)d_in[4];
    const float* W_recv     = (const float*)d_in[5];
    const float* W_send     = (const float*)d_in[6];
    const float* W_recvn    = (const float*)d_in[7];
    const float* W_sendn    = (const float*)d_in[8];
    float* out = (float*)d_out;

    // workspace layout (floats)
    float* g_recv = (float*)d_ws;
    float* g_send = g_recv + (size_t)BN_ * HM_;
    float* g_rn   = g_send + (size_t)BN_ * HM_;
    float* g_sn   = g_rn   + (size_t)BN_ * HM_;
    float* mf     = g_sn   + (size_t)BN_ * HM_;   // BN_ floats

    mask_convert<<<1, 512, 0, stream>>>(mask_raw, mf);
    node_pre<<<BN_ / G_, 256, 0, stream>>>(embeddings, node_feat, mf,
                                           W_recv, W_send, W_recvn, W_sendn,
                                           g_recv, g_send, g_rn, g_sn);
    edge_agg<<<BN_, 256, 0, stream>>>(edge_feat, mf, W_edge,
                                      g_recv, g_send, g_rn, g_sn, out);
}

// Round 2
// 56.491 us; speedup vs baseline: 1.1814x; 1.1814x over previous
//
#include <hip/hip_runtime.h>
#include <math.h>

// Problem constants
#define B_   32
#define N_   64
#define D_   256
#define E_   32
#define DN_  64
#define H_   8
#define M_   32
#define HM_  256      // H_*M_
#define BN_  2048     // B_*N_
#define EPS_ 1e-5f
#define INV_SQRT2 0.70710678118654752f

typedef float f32x4 __attribute__((ext_vector_type(4)));
typedef short bf16x8 __attribute__((ext_vector_type(8)));

union U4S8 { uint4 u; bf16x8 s; };

__device__ __forceinline__ unsigned short f2bf(float f) {
    // RNE float -> bf16 (finite inputs)
    unsigned int u = __float_as_uint(f);
    unsigned int r = (u + 0x7FFFu + ((u >> 16) & 1u)) >> 16;
    return (unsigned short)r;
}

// ---------------------------------------------------------------------------
// Setup kernel: block 0 converts the mask (int32 or byte bools) to float;
// blocks 1..4 pre-pack W_edge into bf16 MFMA B-fragments:
//   WeP[nt*64 + lane] = 8 bf16 { We[k = (lane>>4)*8 + e][n = nt*16 + (lane&15)] }
// Same k-bijection g(hi,e)=hi*8+e is used for the A pack in edge_agg, so the
// MFMA result is correct for any true HW k-order (A/B k-mappings identical).
// ---------------------------------------------------------------------------
__global__ __launch_bounds__(256) void setup_k(const int* __restrict__ mraw,
                                               const float* __restrict__ We,
                                               float* __restrict__ mf,
                                               uint4* __restrict__ WeP) {
    if (blockIdx.x == 0) {
        __shared__ int s_flag;
        const int t = threadIdx.x;
        if (t == 0) s_flag = 0;
        __syncthreads();
        int v0 = mraw[t], v1 = mraw[t + 256];   // first 2048 bytes in either fmt
        if (((v0 | v1) & ~1) != 0) atomicOr(&s_flag, 1);
        __syncthreads();
        const bool bytef = (s_flag != 0);
        const unsigned char* mb = (const unsigned char*)mraw;
        for (int k = t; k < BN_; k += 256)
            mf[k] = bytef ? (mb[k] ? 1.0f : 0.0f) : (mraw[k] ? 1.0f : 0.0f);
    } else {
        const int tau = (blockIdx.x - 1) * 256 + threadIdx.x;  // 0..1023
        const int nt = tau >> 6, l = tau & 63;
        const int hi = l >> 4, n = nt * 16 + (l & 15);
        unsigned short h[8];
        #pragma unroll
        for (int e = 0; e < 8; ++e) h[e] = f2bf(We[(hi * 8 + e) * HM_ + n]);
        uint4 u;
        u.x = (unsigned)h[0] | ((unsigned)h[1] << 16);
        u.y = (unsigned)h[2] | ((unsigned)h[3] << 16);
        u.z = (unsigned)h[4] | ((unsigned)h[5] << 16);
        u.w = (unsigned)h[6] | ((unsigned)h[7] << 16);
        WeP[tau] = u;
    }
}

// ---------------------------------------------------------------------------
// Kernel 1: node precompute (unchanged math, float2-interleaved outputs).
//   g_rr[bn][t] = { recv/sqrt2, rn/sqrt2 }
//   g_ss[bn][t] = { send/sqrt2, sn/sqrt2 }
// ---------------------------------------------------------------------------
#define G_ 4
__global__ __launch_bounds__(256) void node_pre(
        const float* __restrict__ emb, const float* __restrict__ nfeat,
        const float* __restrict__ mf,
        const float* __restrict__ Wr, const float* __restrict__ Ws,
        const float* __restrict__ Wrn, const float* __restrict__ Wsn,
        float2* __restrict__ g_rr, float2* __restrict__ g_ss) {
    __shared__ __align__(16) float ln_s[G_][D_];
    __shared__ __align__(16) float nf_s[G_][DN_];
    __shared__ float rsum[4], rsum2[4];

    const int t = threadIdx.x;
    const int wid = t >> 6;
    const int g0 = blockIdx.x * G_;

    for (int g = 0; g < G_; ++g) {
        const int bn = g0 + g;
        float x = emb[bn * D_ + t];
        float s = x, s2 = x * x;
        #pragma unroll
        for (int k = 32; k >= 1; k >>= 1) {
            s  += __shfl_xor(s, k);
            s2 += __shfl_xor(s2, k);
        }
        if ((t & 63) == 0) { rsum[wid] = s; rsum2[wid] = s2; }
        __syncthreads();
        float S  = rsum[0] + rsum[1] + rsum[2] + rsum[3];
        float S2 = rsum2[0] + rsum2[1] + rsum2[2] + rsum2[3];
        float mu  = S * (1.0f / D_);
        float var = S2 * (1.0f / D_) - mu * mu;
        float mfv = mf[bn];
        ln_s[g][t] = (x - mu) * rsqrtf(var + EPS_) * mfv;
        if (t < DN_) nf_s[g][t] = nfeat[bn * DN_ + t];
        __syncthreads();
    }

    float ar[G_] = {0,0,0,0}, asd[G_] = {0,0,0,0};
    float arn[G_] = {0,0,0,0}, asn[G_] = {0,0,0,0};

    for (int dd = 0; dd < D_; dd += 4) {
        float wr0 = Wr[(dd+0)*HM_ + t], wr1 = Wr[(dd+1)*HM_ + t];
        float wr2 = Wr[(dd+2)*HM_ + t], wr3 = Wr[(dd+3)*HM_ + t];
        float ws0 = Ws[(dd+0)*HM_ + t], ws1 = Ws[(dd+1)*HM_ + t];
        float ws2 = Ws[(dd+2)*HM_ + t], ws3 = Ws[(dd+3)*HM_ + t];
        #pragma unroll
        for (int g = 0; g < G_; ++g) {
            float4 e = *(const float4*)&ln_s[g][dd];
            ar[g]  = fmaf(e.x, wr0, fmaf(e.y, wr1, fmaf(e.z, wr2, fmaf(e.w, wr3, ar[g]))));
            asd[g] = fmaf(e.x, ws0, fmaf(e.y, ws1, fmaf(e.z, ws2, fmaf(e.w, ws3, asd[g]))));
        }
    }
    for (int dd = 0; dd < DN_; dd += 4) {
        float wr0 = Wrn[(dd+0)*HM_ + t], wr1 = Wrn[(dd+1)*HM_ + t];
        float wr2 = Wrn[(dd+2)*HM_ + t], wr3 = Wrn[(dd+3)*HM_ + t];
        float ws0 = Wsn[(dd+0)*HM_ + t], ws1 = Wsn[(dd+1)*HM_ + t];
        float ws2 = Wsn[(dd+2)*HM_ + t], ws3 = Wsn[(dd+3)*HM_ + t];
        #pragma unroll
        for (int g = 0; g < G_; ++g) {
            float4 e = *(const float4*)&nf_s[g][dd];
            arn[g] = fmaf(e.x, wr0, fmaf(e.y, wr1, fmaf(e.z, wr2, fmaf(e.w, wr3, arn[g]))));
            asn[g] = fmaf(e.x, ws0, fmaf(e.y, ws1, fmaf(e.z, ws2, fmaf(e.w, ws3, asn[g]))));
        }
    }

    #pragma unroll
    for (int g = 0; g < G_; ++g) {
        const int bn = g0 + g;
        g_rr[bn * HM_ + t] = make_float2(ar[g]  * INV_SQRT2, arn[g] * INV_SQRT2);
        g_ss[bn * HM_ + t] = make_float2(asd[g] * INV_SQRT2, asn[g] * INV_SQRT2);
    }
}

// ---------------------------------------------------------------------------
// Kernel 2: edge aggregation via bf16 MFMA + gate epilogue + per-head LN.
// One block per receiver (b,j), 4 waves. Block computes
//   ep[64 i][256 t] = (ef_block * mask_i) @ W_edge     (16 MFMAs / wave)
// then per-lane gates each (i,t), sums over i, LNs per head (M=32).
// ---------------------------------------------------------------------------
__global__ __launch_bounds__(256) void edge_agg(
        const float* __restrict__ edge, const float* __restrict__ mf,
        const uint4* __restrict__ WeP,
        const float2* __restrict__ g_rr, const float2* __restrict__ g_ss,
        float* __restrict__ out) {
    const int t  = threadIdx.x;
    const int bn = blockIdx.x;
    const int b  = bn >> 6;
    const int j  = bn & 63;
    const int w  = t >> 6, l = t & 63, hi = l >> 4, lo = l & 15;

    if (mf[bn] == 0.0f) {            // masked receiver -> LN(0) = 0
        out[bn * HM_ + t] = 0.0f;
        return;
    }

    // --- pack A fragments: ldsA[mt*64 + lane] = 8 bf16 of
    //     ef[i = mt*16 + (lane&15)][k = (lane>>4)*8 + e] * mask_i
    __shared__ uint4 ldsA[256];
    {
        const int mt = t >> 6, pl = t & 63, phi = pl >> 4, plo = pl & 15;
        const int i = mt * 16 + plo;
        const float* src = edge + ((size_t)((b * N_ + i) * N_ + j)) * E_ + phi * 8;
        float4 v0 = *(const float4*)src;
        float4 v1 = *(const float4*)(src + 4);
        const float mi = mf[b * N_ + i];
        v0.x *= mi; v0.y *= mi; v0.z *= mi; v0.w *= mi;
        v1.x *= mi; v1.y *= mi; v1.z *= mi; v1.w *= mi;
        uint4 u;
        u.x = (unsigned)f2bf(v0.x) | ((unsigned)f2bf(v0.y) << 16);
        u.y = (unsigned)f2bf(v0.z) | ((unsigned)f2bf(v0.w) << 16);
        u.z = (unsigned)f2bf(v1.x) | ((unsigned)f2bf(v1.y) << 16);
        u.w = (unsigned)f2bf(v1.z) | ((unsigned)f2bf(v1.w) << 16);
        ldsA[t] = u;
    }
    __syncthreads();

    // --- load fragments, 16 MFMAs (K=32 = E in one step)
    U4S8 a4[4], b4[4];
    #pragma unroll
    for (int mt = 0; mt < 4; ++mt) a4[mt].u = ldsA[mt * 64 + l];
    #pragma unroll
    for (int nl = 0; nl < 4; ++nl) b4[nl].u = WeP[(w * 4 + nl) * 64 + l];

    const f32x4 zero = {0.0f, 0.0f, 0.0f, 0.0f};
    f32x4 acc[4][4];
    #pragma unroll
    for (int mt = 0; mt < 4; ++mt)
        #pragma unroll
        for (int nl = 0; nl < 4; ++nl)
            acc[mt][nl] = __builtin_amdgcn_mfma_f32_16x16x32_bf16(a4[mt].s, b4[nl].s, zero, 0, 0, 0);

    // --- gate epilogue: lane holds ep[i = mt*16 + hi*4 + r][t = w*64 + nl*16 + lo]
    float2 rr[4];
    #pragma unroll
    for (int nl = 0; nl < 4; ++nl) rr[nl] = g_rr[bn * HM_ + w * 64 + nl * 16 + lo];

    float upd[4] = {0.0f, 0.0f, 0.0f, 0.0f};
    #pragma unroll
    for (int mt = 0; mt < 4; ++mt) {
        #pragma unroll
        for (int r = 0; r < 4; ++r) {
            const int i = mt * 16 + hi * 4 + r;
            const float2* ssrow = g_ss + (size_t)(b * N_ + i) * HM_;
            #pragma unroll
            for (int nl = 0; nl < 4; ++nl) {
                float2 ss = ssrow[w * 64 + nl * 16 + lo];
                float ep = acc[mt][nl][r];
                float tx = rr[nl].x + ss.x;                         // (recv+send)/sqrt2
                float E1 = __expf(2.0f * tx);
                float th = fmaf(-2.0f, __builtin_amdgcn_rcpf(E1 + 1.0f), 1.0f);
                float z  = rr[nl].y + ss.y;                         // (rn+sn)/sqrt2
                float sg = __builtin_amdgcn_rcpf(1.0f + __expf(-z));
                upd[nl] = fmaf(th * sg, ep, upd[nl]);
            }
        }
    }

    // --- reduce over the 4 hi-groups (completes sum over all 64 senders)
    #pragma unroll
    for (int nl = 0; nl < 4; ++nl) {
        upd[nl] += __shfl_xor(upd[nl], 16);
        upd[nl] += __shfl_xor(upd[nl], 32);
    }

    // --- per-head LN (head0: nl 0,1 ; head1: nl 2,3 within this wave's 64 ch)
    float s0 = upd[0] + upd[1], q0 = upd[0] * upd[0] + upd[1] * upd[1];
    float s1 = upd[2] + upd[3], q1 = upd[2] * upd[2] + upd[3] * upd[3];
    #pragma unroll
    for (int k = 8; k >= 1; k >>= 1) {
        s0 += __shfl_xor(s0, k); q0 += __shfl_xor(q0, k);
        s1 += __shfl_xor(s1, k); q1 += __shfl_xor(q1, k);
    }
    float mu0 = s0 * (1.0f / M_), va0 = q0 * (1.0f / M_) - mu0 * mu0;
    float mu1 = s1 * (1.0f / M_), va1 = q1 * (1.0f / M_) - mu1 * mu1;
    float rs0 = rsqrtf(va0 + EPS_), rs1 = rsqrtf(va1 + EPS_);
    float val = upd[hi];
    float o = (hi < 2) ? (val - mu0) * rs0 : (val - mu1) * rs1;
    out[bn * HM_ + w * 64 + l] = o;    // t = w*64 + hi*16 + lo = w*64 + l
}

// ---------------------------------------------------------------------------
extern "C" void kernel_launch(void* const* d_in, const int* in_sizes, int n_in,
                              void* d_out, int out_size, void* d_ws, size_t ws_size,
                              hipStream_t stream) {
    const float* embeddings = (const float*)d_in[0];
    const float* edge_feat  = (const float*)d_in[1];
    const int*   mask_raw   = (const int*)d_in[2];
    const float* node_feat  = (const float*)d_in[3];
    const float* W_edge     = (const float*)d_in[4];
    const float* W_recv     = (const float*)d_in[5];
    const float* W_send     = (const float*)d_in[6];
    const float* W_recvn    = (const float*)d_in[7];
    const float* W_sendn    = (const float*)d_in[8];
    float* out = (float*)d_out;

    // workspace layout
    float2* g_ss = (float2*)d_ws;                      // 4 MB
    float2* g_rr = g_ss + (size_t)BN_ * HM_;           // 4 MB
    uint4*  WeP  = (uint4*)(g_rr + (size_t)BN_ * HM_); // 16 KB
    float*  mf   = (float*)(WeP + 1024);               // 8 KB

    setup_k<<<5, 256, 0, stream>>>(mask_raw, W_edge, mf, WeP);
    node_pre<<<BN_ / G_, 256, 0, stream>>>(embeddings, node_feat, mf,
                                           W_recv, W_send, W_recvn, W_sendn,
                                           g_rr, g_ss);
    edge_agg<<<BN_, 256, 0, stream>>>(edge_feat, mf, WeP, g_rr, g_ss, out);
}

// Round 3
// 55.380 us; speedup vs baseline: 1.2051x; 1.0201x over previous
//
#include <hip/hip_runtime.h>
#include <math.h>

// Problem constants
#define B_   32
#define N_   64
#define D_   256
#define E_   32
#define DN_  64
#define H_   8
#define M_   32
#define HM_  256      // H_*M_
#define BN_  2048     // B_*N_
#define EPS_ 1e-5f
#define INV_SQRT2 0.70710678118654752f

typedef float f32x4 __attribute__((ext_vector_type(4)));
typedef short bf16x8 __attribute__((ext_vector_type(8)));

union U4S8 { uint4 u; bf16x8 s; };

__device__ __forceinline__ unsigned short f2bf(float f) {
    // RNE float -> bf16 (finite inputs)
    unsigned int u = __float_as_uint(f);
    unsigned int r = (u + 0x7FFFu + ((u >> 16) & 1u)) >> 16;
    return (unsigned short)r;
}

// ---------------------------------------------------------------------------
// Setup kernel (5 blocks):
//  block 0: mask (int32 or byte bool) -> float mf[BN_]; per-batch sender
//           compaction: cnt[b], sidx[b][p] (-1 pad), pos[b][i] (-1 if masked)
//  blocks 1-4: pre-pack W_edge into bf16 MFMA B-fragments.
//    WeP[nt*64+lane] = 8 bf16 { We[k=(lane>>4)*8+e][n=nt*16+(lane&15)] }
//  The same k-bijection g(hi,e)=hi*8+e is used for the A pack in edge_agg,
//  so the MFMA dot product is correct for any true HW k-order.
// ---------------------------------------------------------------------------
__global__ __launch_bounds__(256) void setup_k(const int* __restrict__ mraw,
                                               const float* __restrict__ We,
                                               float* __restrict__ mf,
                                               uint4* __restrict__ WeP,
                                               int* __restrict__ cnt,
                                               int* __restrict__ sidx,
                                               int* __restrict__ pos) {
    if (blockIdx.x == 0) {
        __shared__ int s_flag;
        __shared__ float smf[BN_];
        const int t = threadIdx.x;
        if (t == 0) s_flag = 0;
        __syncthreads();
        int v0 = mraw[t], v1 = mraw[t + 256];   // first 2048 bytes, either fmt
        if (((v0 | v1) & ~1) != 0) atomicOr(&s_flag, 1);
        __syncthreads();
        const bool bytef = (s_flag != 0);
        const unsigned char* mb = (const unsigned char*)mraw;
        for (int k = t; k < BN_; k += 256) {
            float v = bytef ? (mb[k] ? 1.0f : 0.0f) : (mraw[k] ? 1.0f : 0.0f);
            smf[k] = v;
            mf[k] = v;
        }
        __syncthreads();
        if (t < B_) {                 // one thread per batch: serial compaction
            int c = 0;
            for (int i = 0; i < N_; ++i) {
                if (smf[t * N_ + i] > 0.5f) {
                    sidx[t * N_ + c] = i;
                    pos[t * N_ + i] = c;
                    ++c;
                } else {
                    pos[t * N_ + i] = -1;
                }
            }
            cnt[t] = c;
            for (int p = c; p < N_; ++p) sidx[t * N_ + p] = -1;
        }
    } else {
        const int tau = (blockIdx.x - 1) * 256 + threadIdx.x;  // 0..1023
        const int nt = tau >> 6, l = tau & 63;
        const int hi = l >> 4, n = nt * 16 + (l & 15);
        unsigned short h[8];
        #pragma unroll
        for (int e = 0; e < 8; ++e) h[e] = f2bf(We[(hi * 8 + e) * HM_ + n]);
        uint4 u;
        u.x = (unsigned)h[0] | ((unsigned)h[1] << 16);
        u.y = (unsigned)h[2] | ((unsigned)h[3] << 16);
        u.z = (unsigned)h[4] | ((unsigned)h[5] << 16);
        u.w = (unsigned)h[6] | ((unsigned)h[7] << 16);
        WeP[tau] = u;
    }
}

// ---------------------------------------------------------------------------
// Kernel 1: node precompute, G=8 nodes/block (256 blocks x 256 threads).
//   g_rr[bn][t]          = { recv/sqrt2, rn/sqrt2 }    (receiver-indexed)
//   g_ssC[b*64+pos][t]   = { send/sqrt2, sn/sqrt2 }    (compacted senders)
// Wave-parallel LN: wave w handles nodes w and w+4 (one barrier total).
// ---------------------------------------------------------------------------
#define G_ 8
__global__ __launch_bounds__(256) void node_pre(
        const float* __restrict__ emb, const float* __restrict__ nfeat,
        const float* __restrict__ mf, const int* __restrict__ pos,
        const float* __restrict__ Wr, const float* __restrict__ Ws,
        const float* __restrict__ Wrn, const float* __restrict__ Wsn,
        float2* __restrict__ g_rr, float2* __restrict__ g_ssC) {
    __shared__ __align__(16) float ln_s[G_][D_];
    __shared__ __align__(16) float nf_s[G_][DN_];

    const int t = threadIdx.x;
    const int w = t >> 6, l = t & 63;
    const int g0 = blockIdx.x * G_;

    #pragma unroll
    for (int gg = 0; gg < 2; ++gg) {
        const int g = w + gg * 4;
        const int bn = g0 + g;
        float4 x = *(const float4*)&emb[bn * D_ + l * 4];
        float s  = x.x + x.y + x.z + x.w;
        float s2 = x.x * x.x + x.y * x.y + x.z * x.z + x.w * x.w;
        #pragma unroll
        for (int k = 32; k >= 1; k >>= 1) {
            s  += __shfl_xor(s, k);
            s2 += __shfl_xor(s2, k);
        }
        float mu  = s * (1.0f / D_);
        float var = s2 * (1.0f / D_) - mu * mu;
        float rs  = rsqrtf(var + EPS_) * mf[bn];
        float4 o;
        o.x = (x.x - mu) * rs; o.y = (x.y - mu) * rs;
        o.z = (x.z - mu) * rs; o.w = (x.w - mu) * rs;
        *(float4*)&ln_s[g][l * 4] = o;
        nf_s[g][l] = nfeat[bn * DN_ + l];
    }
    __syncthreads();

    float ar[G_], asd[G_], arn[G_], asn[G_];
    #pragma unroll
    for (int g = 0; g < G_; ++g) { ar[g] = 0; asd[g] = 0; arn[g] = 0; asn[g] = 0; }

    for (int dd = 0; dd < D_; dd += 4) {
        float wr0 = Wr[(dd+0)*HM_ + t], wr1 = Wr[(dd+1)*HM_ + t];
        float wr2 = Wr[(dd+2)*HM_ + t], wr3 = Wr[(dd+3)*HM_ + t];
        float ws0 = Ws[(dd+0)*HM_ + t], ws1 = Ws[(dd+1)*HM_ + t];
        float ws2 = Ws[(dd+2)*HM_ + t], ws3 = Ws[(dd+3)*HM_ + t];
        #pragma unroll
        for (int g = 0; g < G_; ++g) {
            float4 e = *(const float4*)&ln_s[g][dd];
            ar[g]  = fmaf(e.x, wr0, fmaf(e.y, wr1, fmaf(e.z, wr2, fmaf(e.w, wr3, ar[g]))));
            asd[g] = fmaf(e.x, ws0, fmaf(e.y, ws1, fmaf(e.z, ws2, fmaf(e.w, ws3, asd[g]))));
        }
    }
    for (int dd = 0; dd < DN_; dd += 4) {
        float wr0 = Wrn[(dd+0)*HM_ + t], wr1 = Wrn[(dd+1)*HM_ + t];
        float wr2 = Wrn[(dd+2)*HM_ + t], wr3 = Wrn[(dd+3)*HM_ + t];
        float ws0 = Wsn[(dd+0)*HM_ + t], ws1 = Wsn[(dd+1)*HM_ + t];
        float ws2 = Wsn[(dd+2)*HM_ + t], ws3 = Wsn[(dd+3)*HM_ + t];
        #pragma unroll
        for (int g = 0; g < G_; ++g) {
            float4 e = *(const float4*)&nf_s[g][dd];
            arn[g] = fmaf(e.x, wr0, fmaf(e.y, wr1, fmaf(e.z, wr2, fmaf(e.w, wr3, arn[g]))));
            asn[g] = fmaf(e.x, ws0, fmaf(e.y, ws1, fmaf(e.z, ws2, fmaf(e.w, ws3, asn[g]))));
        }
    }

    #pragma unroll
    for (int g = 0; g < G_; ++g) {
        const int bn = g0 + g;
        const int b  = bn >> 6;
        g_rr[bn * HM_ + t] = make_float2(ar[g] * INV_SQRT2, arn[g] * INV_SQRT2);
        const int p = pos[bn];
        if (p >= 0)
            g_ssC[(size_t)(b * N_ + p) * HM_ + t] =
                make_float2(asd[g] * INV_SQRT2, asn[g] * INV_SQRT2);
    }
}

// ---------------------------------------------------------------------------
// Kernel 2: edge aggregation via bf16 MFMA + gate epilogue + per-head LN.
// One block per receiver (b,j), 4 waves. Senders compacted to cnt[b] rows:
//   ep[p][256 t] = ef[b, sidx[p], j, :] @ W_edge      (4 MFMAs per mt-subtile)
// Only ceil(cnt/16) of the 4 mt-subtiles are processed (wave-uniform branch).
// ---------------------------------------------------------------------------
__global__ __launch_bounds__(256) void edge_agg(
        const float* __restrict__ edge, const float* __restrict__ mf,
        const int* __restrict__ cnt, const int* __restrict__ sidx,
        const uint4* __restrict__ WeP,
        const float2* __restrict__ g_rr, const float2* __restrict__ g_ssC,
        float* __restrict__ out) {
    const int t  = threadIdx.x;
    const int bn = blockIdx.x;
    const int b  = bn >> 6;
    const int j  = bn & 63;
    const int w  = t >> 6, l = t & 63, hi = l >> 4, lo = l & 15;

    if (mf[bn] == 0.0f) {            // masked receiver -> LN(0) = 0
        out[bn * HM_ + t] = 0.0f;
        return;
    }
    const int cb = cnt[b];           // wave-uniform

    // --- pack A fragments: ldsA[mt*64 + lane] = 8 bf16 of
    //     ef[b, sidx[mt*16+(lane&15)], j][k = (lane>>4)*8 + e]   (0 if pad)
    __shared__ uint4 ldsA[256];
    {
        const int mt = t >> 6, pl = t & 63, phi = pl >> 4, plo = pl & 15;
        const int si = sidx[b * N_ + mt * 16 + plo];
        uint4 u = make_uint4(0, 0, 0, 0);
        if (si >= 0) {
            const float* src = edge + ((size_t)((b * N_ + si) * N_ + j)) * E_ + phi * 8;
            float4 v0 = *(const float4*)src;
            float4 v1 = *(const float4*)(src + 4);
            u.x = (unsigned)f2bf(v0.x) | ((unsigned)f2bf(v0.y) << 16);
            u.y = (unsigned)f2bf(v0.z) | ((unsigned)f2bf(v0.w) << 16);
            u.z = (unsigned)f2bf(v1.x) | ((unsigned)f2bf(v1.y) << 16);
            u.w = (unsigned)f2bf(v1.z) | ((unsigned)f2bf(v1.w) << 16);
        }
        ldsA[t] = u;
    }
    __syncthreads();

    // --- B fragments (block-invariant, from ws)
    U4S8 b4[4];
    #pragma unroll
    for (int nl = 0; nl < 4; ++nl) b4[nl].u = WeP[(w * 4 + nl) * 64 + l];

    float2 rr[4];
    #pragma unroll
    for (int nl = 0; nl < 4; ++nl) rr[nl] = g_rr[bn * HM_ + w * 64 + nl * 16 + lo];

    const f32x4 zero = {0.0f, 0.0f, 0.0f, 0.0f};
    float upd[4] = {0.0f, 0.0f, 0.0f, 0.0f};

    #pragma unroll
    for (int mt = 0; mt < 4; ++mt) {
        if (mt * 16 < cb) {          // wave-uniform: skip empty sender subtiles
            U4S8 a4; a4.u = ldsA[mt * 64 + l];
            f32x4 acc[4];
            #pragma unroll
            for (int nl = 0; nl < 4; ++nl)
                acc[nl] = __builtin_amdgcn_mfma_f32_16x16x32_bf16(a4.s, b4[nl].s, zero, 0, 0, 0);

            // gate: lane holds ep[p = mt*16 + hi*4 + r][ch = w*64 + nl*16 + lo]
            #pragma unroll
            for (int r = 0; r < 4; ++r) {
                const int p = mt * 16 + hi * 4 + r;
                const float2* ssrow = g_ssC + (size_t)(b * N_ + p) * HM_;
                #pragma unroll
                for (int nl = 0; nl < 4; ++nl) {
                    float2 ss = ssrow[w * 64 + nl * 16 + lo];
                    float ep = acc[nl][r];
                    float tx = rr[nl].x + ss.x;                      // (recv+send)/sqrt2
                    float E1 = __expf(2.0f * tx);
                    float th = fmaf(-2.0f, __builtin_amdgcn_rcpf(E1 + 1.0f), 1.0f);
                    float z  = rr[nl].y + ss.y;                      // (rn+sn)/sqrt2
                    float sg = __builtin_amdgcn_rcpf(1.0f + __expf(-z));
                    upd[nl] = fmaf(th * sg, ep, upd[nl]);
                }
            }
        }
    }

    // --- reduce over the 4 hi-groups (completes sum over senders)
    #pragma unroll
    for (int nl = 0; nl < 4; ++nl) {
        upd[nl] += __shfl_xor(upd[nl], 16);
        upd[nl] += __shfl_xor(upd[nl], 32);
    }

    // --- per-head LN (head0: nl 0,1 ; head1: nl 2,3 within this wave's 64 ch)
    float s0 = upd[0] + upd[1], q0 = upd[0] * upd[0] + upd[1] * upd[1];
    float s1 = upd[2] + upd[3], q1 = upd[2] * upd[2] + upd[3] * upd[3];
    #pragma unroll
    for (int k = 8; k >= 1; k >>= 1) {
        s0 += __shfl_xor(s0, k); q0 += __shfl_xor(q0, k);
        s1 += __shfl_xor(s1, k); q1 += __shfl_xor(q1, k);
    }
    float mu0 = s0 * (1.0f / M_), va0 = q0 * (1.0f / M_) - mu0 * mu0;
    float mu1 = s1 * (1.0f / M_), va1 = q1 * (1.0f / M_) - mu1 * mu1;
    float rs0 = rsqrtf(va0 + EPS_), rs1 = rsqrtf(va1 + EPS_);
    float val = upd[hi];
    float o = (hi < 2) ? (val - mu0) * rs0 : (val - mu1) * rs1;
    out[bn * HM_ + w * 64 + l] = o;    // t = w*64 + hi*16 + lo = w*64 + l
}

// ---------------------------------------------------------------------------
extern "C" void kernel_launch(void* const* d_in, const int* in_sizes, int n_in,
                              void* d_out, int out_size, void* d_ws, size_t ws_size,
                              hipStream_t stream) {
    const float* embeddings = (const float*)d_in[0];
    const float* edge_feat  = (const float*)d_in[1];
    const int*   mask_raw   = (const int*)d_in[2];
    const float* node_feat  = (const float*)d_in[3];
    const float* W_edge     = (const float*)d_in[4];
    const float* W_recv     = (const float*)d_in[5];
    const float* W_send     = (const float*)d_in[6];
    const float* W_recvn    = (const float*)d_in[7];
    const float* W_sendn    = (const float*)d_in[8];
    float* out = (float*)d_out;

    // workspace layout
    float2* g_ssC = (float2*)d_ws;                       // 4 MB
    float2* g_rr  = g_ssC + (size_t)BN_ * HM_;           // 4 MB
    uint4*  WeP   = (uint4*)(g_rr + (size_t)BN_ * HM_);  // 16 KB
    float*  mf    = (float*)(WeP + 1024);                // 8 KB
    int*    cnt   = (int*)(mf + BN_);                    // 128 B
    int*    sidx  = cnt + 32;                            // 8 KB
    int*    pos   = sidx + BN_;                          // 8 KB

    setup_k<<<5, 256, 0, stream>>>(mask_raw, W_edge, mf, WeP, cnt, sidx, pos);
    node_pre<<<BN_ / G_, 256, 0, stream>>>(embeddings, node_feat, mf, pos,
                                           W_recv, W_send, W_recvn, W_sendn,
                                           g_rr, g_ssC);
    edge_agg<<<BN_, 256, 0, stream>>>(edge_feat, mf, cnt, sidx, WeP,
                                      g_rr, g_ssC, out);
}

// Round 4
// 42.689 us; speedup vs baseline: 1.5634x; 1.2973x over previous
//
#include <hip/hip_runtime.h>
#include <hip/hip_bf16.h>
#include <math.h>

// Problem constants
#define B_   32
#define N_   64
#define D_   256
#define E_   32
#define DN_  64
#define H_   8
#define M_   32
#define HM_  256      // H_*M_
#define BN_  2048     // B_*N_
#define EPS_ 1e-5f
#define INV_SQRT2 0.70710678118654752f

typedef float f32x4 __attribute__((ext_vector_type(4)));
typedef short bf16x8 __attribute__((ext_vector_type(8)));
union U4S8 { uint4 u; bf16x8 s; };

// RNE pack of two f32 -> one u32 of 2 bf16 (low = a). Compiler should emit
// v_cvt_pk_bf16_f32.
__device__ __forceinline__ unsigned pk2(float a, float b) {
    union { __hip_bfloat162 h; unsigned u; } cv;
    cv.h = __float22bfloat162_rn(make_float2(a, b));
    return cv.u;
}

// MFMA conventions used by BOTH kernels (validated in rounds 2-3):
//  A-frag: lane holds row (l&15), k-elems g(hi,e)=hi*8+e  (hi=l>>4, e=0..7)
//  B-frag: lane holds col (l&15), same k-bijection
//  C/D   : col = lane&15, row = (lane>>4)*4 + reg          (m89 layout)
// Any consistent k-bijection on A and B yields the correct dot product.

// ---------------------------------------------------------------------------
// Kernel 1: per-batch node kernel (fuses old setup + node_pre).
// Grid 64 = 2 blocks per batch (half = low bit; each half owns 128 channels).
// Phases: mask convert+compaction -> LN(emb)*mask -> bf16 LDS staging ->
// MFMA projections (recv/send over D=256, rn/sn over DN=64) -> stores:
//   g_rr [bn][ch]        = { recv/sqrt2, rn/sqrt2 }   (receiver-indexed)
//   g_ssC[b*64+p][ch]    = { send/sqrt2, sn/sqrt2 }   (compacted senders)
// Pad rows (p >= cnt) zero-filled so K2 never reads uninitialized ws.
// ---------------------------------------------------------------------------
__global__ __launch_bounds__(256, 1) void node_k(
        const float* __restrict__ emb, const float* __restrict__ nfeat,
        const int* __restrict__ mraw,
        const float* __restrict__ Wr, const float* __restrict__ Ws,
        const float* __restrict__ Wrn, const float* __restrict__ Wsn,
        float2* __restrict__ g_rr, float2* __restrict__ g_ssC,
        int* __restrict__ cnt, int* __restrict__ sidx,
        unsigned long long* __restrict__ mask64) {
    const int t = threadIdx.x;
    const int w = t >> 6, l = t & 63, hi = l >> 4, lo = l & 15;
    const int b = blockIdx.x >> 1, half = blockIdx.x & 1;
    const int nbase = half * 128 + w * 32;      // this wave's 32-channel slice

    __shared__ int s_flag, cnt_sh;
    __shared__ float mfb[N_];
    __shared__ int sidx_s[N_], pos_s[N_];
    __shared__ __align__(16) unsigned short eln[64 * 256];  // 32 KB bf16 LN(emb)*mask, XOR-swizzled
    __shared__ __align__(16) unsigned short nfs[64 * 64];   // 8 KB bf16 node_features, XOR-swizzled

    // --- mask format detect (first 2048 bytes; int32 values outside {0,1} => byte bools)
    if (t == 0) s_flag = 0;
    __syncthreads();
    {
        int v0 = mraw[t], v1 = mraw[t + 256];
        if (((v0 | v1) & ~1) != 0) atomicOr(&s_flag, 1);
    }
    __syncthreads();
    const bool bytef = (s_flag != 0);
    if (t < N_) {
        const unsigned char* mb = (const unsigned char*)mraw;
        const int k = b * N_ + t;
        mfb[t] = bytef ? (mb[k] ? 1.0f : 0.0f) : (mraw[k] ? 1.0f : 0.0f);
    }
    __syncthreads();
    if (t == 0) {                    // serial compaction over 64 senders
        int c = 0; unsigned long long bits = 0;
        for (int i = 0; i < N_; ++i) {
            if (mfb[i] > 0.5f) { bits |= (1ull << i); sidx_s[c] = i; pos_s[i] = c; ++c; }
            else pos_s[i] = -1;
        }
        cnt_sh = c;
        for (int p = c; p < N_; ++p) sidx_s[p] = -1;
        if (half == 0) { cnt[b] = c; mask64[b] = bits; }
    }
    __syncthreads();
    if (half == 0 && t < N_) sidx[b * N_ + t] = sidx_s[t];

    // --- LN phase: wave w handles rows w*16..w*16+15; bf16 into swizzled LDS
    for (int rr = 0; rr < 16; ++rr) {
        const int i = w * 16 + rr;
        float4 x = *(const float4*)(emb + (size_t)(b * N_ + i) * D_ + l * 4);
        float s  = x.x + x.y + x.z + x.w;
        float s2 = x.x*x.x + x.y*x.y + x.z*x.z + x.w*x.w;
        #pragma unroll
        for (int k = 32; k >= 1; k >>= 1) { s += __shfl_xor(s, k); s2 += __shfl_xor(s2, k); }
        float mu  = s * (1.0f / D_);
        float var = s2 * (1.0f / D_) - mu * mu;
        float rs  = rsqrtf(var + EPS_) * mfb[i];
        unsigned p0 = pk2((x.x - mu) * rs, (x.y - mu) * rs);
        unsigned p1 = pk2((x.z - mu) * rs, (x.w - mu) * rs);
        unsigned off = (unsigned)(i * 512) + (((unsigned)(l * 8)) ^ (((unsigned)(i & 15)) << 4));
        *(uint2*)((char*)eln + off) = make_uint2(p0, p1);
    }
    // --- node_features -> bf16 LDS (64 x 64)
    #pragma unroll
    for (int it = 0; it < 4; ++it) {
        const int idx = it * 1024 + t * 4;
        const int r = idx >> 6, c = idx & 63;
        float4 x = *(const float4*)(nfeat + (size_t)(b * N_ + r) * DN_ + c);
        unsigned p0 = pk2(x.x, x.y), p1 = pk2(x.z, x.w);
        unsigned off = (unsigned)(r * 128) + (((unsigned)(c * 2)) ^ (((unsigned)(r & 7)) << 4));
        *(uint2*)((char*)nfs + off) = make_uint2(p0, p1);
    }
    __syncthreads();

    // --- MFMA phase: acc[mt 0..3][nt 0..1] for recv/send (K=256) + rn/sn (K=64)
    f32x4 aR[4][2], aS[4][2], aRN[4][2], aSN[4][2];
    #pragma unroll
    for (int mt = 0; mt < 4; ++mt)
        #pragma unroll
        for (int nt = 0; nt < 2; ++nt) {
            aR[mt][nt] = (f32x4){0,0,0,0}; aS[mt][nt] = (f32x4){0,0,0,0};
            aRN[mt][nt] = (f32x4){0,0,0,0}; aSN[mt][nt] = (f32x4){0,0,0,0};
        }

    for (int ks = 0; ks < 8; ++ks) {
        U4S8 af[4];
        #pragma unroll
        for (int mt = 0; mt < 4; ++mt) {
            const int i = mt * 16 + lo;
            unsigned o = (unsigned)(ks * 64 + hi * 16);
            af[mt].u = *(const uint4*)((const char*)eln +
                          (unsigned)(i * 512) + (o ^ (((unsigned)(i & 15)) << 4)));
        }
        U4S8 br[2], bs[2];
        #pragma unroll
        for (int nt = 0; nt < 2; ++nt) {
            const int n = nbase + nt * 16 + lo;
            const float* wr = Wr + (size_t)(ks * 32 + hi * 8) * HM_ + n;
            const float* ws = Ws + (size_t)(ks * 32 + hi * 8) * HM_ + n;
            float r0=wr[0*HM_], r1=wr[1*HM_], r2=wr[2*HM_], r3=wr[3*HM_];
            float r4=wr[4*HM_], r5=wr[5*HM_], r6=wr[6*HM_], r7=wr[7*HM_];
            br[nt].u = make_uint4(pk2(r0,r1), pk2(r2,r3), pk2(r4,r5), pk2(r6,r7));
            float s0=ws[0*HM_], s1=ws[1*HM_], s2=ws[2*HM_], s3=ws[3*HM_];
            float s4=ws[4*HM_], s5=ws[5*HM_], s6=ws[6*HM_], s7=ws[7*HM_];
            bs[nt].u = make_uint4(pk2(s0,s1), pk2(s2,s3), pk2(s4,s5), pk2(s6,s7));
        }
        #pragma unroll
        for (int mt = 0; mt < 4; ++mt)
            #pragma unroll
            for (int nt = 0; nt < 2; ++nt) {
                aR[mt][nt] = __builtin_amdgcn_mfma_f32_16x16x32_bf16(af[mt].s, br[nt].s, aR[mt][nt], 0, 0, 0);
                aS[mt][nt] = __builtin_amdgcn_mfma_f32_16x16x32_bf16(af[mt].s, bs[nt].s, aS[mt][nt], 0, 0, 0);
            }
        if (ks < 2) {                 // node-feature GEMMs, K=64
            U4S8 a2[4];
            #pragma unroll
            for (int mt = 0; mt < 4; ++mt) {
                const int i = mt * 16 + lo;
                unsigned o = (unsigned)(ks * 64 + hi * 16);
                a2[mt].u = *(const uint4*)((const char*)nfs +
                              (unsigned)(i * 128) + (o ^ (((unsigned)(i & 7)) << 4)));
            }
            U4S8 brn[2], bsn[2];
            #pragma unroll
            for (int nt = 0; nt < 2; ++nt) {
                const int n = nbase + nt * 16 + lo;
                const float* wr = Wrn + (size_t)(ks * 32 + hi * 8) * HM_ + n;
                const float* ws = Wsn + (size_t)(ks * 32 + hi * 8) * HM_ + n;
                float r0=wr[0*HM_], r1=wr[1*HM_], r2=wr[2*HM_], r3=wr[3*HM_];
                float r4=wr[4*HM_], r5=wr[5*HM_], r6=wr[6*HM_], r7=wr[7*HM_];
                brn[nt].u = make_uint4(pk2(r0,r1), pk2(r2,r3), pk2(r4,r5), pk2(r6,r7));
                float s0=ws[0*HM_], s1=ws[1*HM_], s2=ws[2*HM_], s3=ws[3*HM_];
                float s4=ws[4*HM_], s5=ws[5*HM_], s6=ws[6*HM_], s7=ws[7*HM_];
                bsn[nt].u = make_uint4(pk2(s0,s1), pk2(s2,s3), pk2(s4,s5), pk2(s6,s7));
            }
            #pragma unroll
            for (int mt = 0; mt < 4; ++mt)
                #pragma unroll
                for (int nt = 0; nt < 2; ++nt) {
                    aRN[mt][nt] = __builtin_amdgcn_mfma_f32_16x16x32_bf16(a2[mt].s, brn[nt].s, aRN[mt][nt], 0, 0, 0);
                    aSN[mt][nt] = __builtin_amdgcn_mfma_f32_16x16x32_bf16(a2[mt].s, bsn[nt].s, aSN[mt][nt], 0, 0, 0);
                }
        }
    }

    // --- epilogue stores
    const int cb = cnt_sh;
    #pragma unroll
    for (int mt = 0; mt < 4; ++mt) {
        #pragma unroll
        for (int r = 0; r < 4; ++r) {
            const int i = mt * 16 + hi * 4 + r;
            const int p = pos_s[i];
            #pragma unroll
            for (int nt = 0; nt < 2; ++nt) {
                const int n = nbase + nt * 16 + lo;
                g_rr[(size_t)(b * N_ + i) * HM_ + n] =
                    make_float2(aR[mt][nt][r] * INV_SQRT2, aRN[mt][nt][r] * INV_SQRT2);
                if (p >= 0)
                    g_ssC[(size_t)(b * N_ + p) * HM_ + n] =
                        make_float2(aS[mt][nt][r] * INV_SQRT2, aSN[mt][nt][r] * INV_SQRT2);
            }
        }
    }
    // zero-fill pad sender rows so K2 reads deterministic zeros
    for (int pp = cb + w; pp < N_; pp += 4) {
        float4 z = {0, 0, 0, 0};
        *(float4*)&g_ssC[(size_t)(b * N_ + pp) * HM_ + half * 128 + l * 2] = z;
    }
}

// ---------------------------------------------------------------------------
// Kernel 2: edge aggregation via bf16 MFMA + gate epilogue + per-head LN.
// One block per receiver (b,j), 4 waves. Senders compacted to cnt[b] rows.
// B-fragments packed from W_edge directly (L2-hot, cheap with cvt_pk).
// ---------------------------------------------------------------------------
__global__ __launch_bounds__(256) void edge_agg(
        const float* __restrict__ edge,
        const unsigned long long* __restrict__ mask64,
        const int* __restrict__ cnt, const int* __restrict__ sidx,
        const float* __restrict__ We,
        const float2* __restrict__ g_rr, const float2* __restrict__ g_ssC,
        float* __restrict__ out) {
    const int t  = threadIdx.x;
    const int bn = blockIdx.x;
    const int b  = bn >> 6;
    const int j  = bn & 63;
    const int w  = t >> 6, l = t & 63, hi = l >> 4, lo = l & 15;

    if (!((mask64[b] >> j) & 1ull)) {     // masked receiver -> LN(0) = 0
        out[bn * HM_ + t] = 0.0f;
        return;
    }
    const int cb = cnt[b];                // wave-uniform

    // --- pack A fragments: ldsA[mt*64 + lane] = 8 bf16 of
    //     ef[b, sidx[mt*16+(lane&15)], j][k = (lane>>4)*8 + e]   (0 if pad)
    __shared__ uint4 ldsA[256];
    {
        const int mt = t >> 6, phi = (t >> 4) & 3, plo = t & 15;
        const int si = sidx[b * N_ + mt * 16 + plo];
        uint4 u = make_uint4(0, 0, 0, 0);
        if (si >= 0) {
            const float* src = edge + ((size_t)((b * N_ + si) * N_ + j)) * E_ + phi * 8;
            float4 v0 = *(const float4*)src;
            float4 v1 = *(const float4*)(src + 4);
            u = make_uint4(pk2(v0.x, v0.y), pk2(v0.z, v0.w),
                           pk2(v1.x, v1.y), pk2(v1.z, v1.w));
        }
        ldsA[t] = u;
    }
    __syncthreads();

    // --- B fragments from W_edge (K=32=E in one step)
    U4S8 b4[4];
    #pragma unroll
    for (int nl = 0; nl < 4; ++nl) {
        const int n = w * 64 + nl * 16 + lo;
        const float* wp = We + (size_t)(hi * 8) * HM_ + n;
        float w0=wp[0*HM_], w1=wp[1*HM_], w2=wp[2*HM_], w3=wp[3*HM_];
        float w4=wp[4*HM_], w5=wp[5*HM_], w6=wp[6*HM_], w7=wp[7*HM_];
        b4[nl].u = make_uint4(pk2(w0,w1), pk2(w2,w3), pk2(w4,w5), pk2(w6,w7));
    }

    float2 rr[4];
    #pragma unroll
    for (int nl = 0; nl < 4; ++nl) rr[nl] = g_rr[bn * HM_ + w * 64 + nl * 16 + lo];

    const f32x4 zero = {0.0f, 0.0f, 0.0f, 0.0f};
    float upd[4] = {0.0f, 0.0f, 0.0f, 0.0f};

    #pragma unroll
    for (int mt = 0; mt < 4; ++mt) {
        if (mt * 16 < cb) {               // wave-uniform subtile skip
            U4S8 a4; a4.u = ldsA[mt * 64 + l];
            f32x4 acc[4];
            #pragma unroll
            for (int nl = 0; nl < 4; ++nl)
                acc[nl] = __builtin_amdgcn_mfma_f32_16x16x32_bf16(a4.s, b4[nl].s, zero, 0, 0, 0);

            // gate: lane holds ep[p = mt*16 + hi*4 + r][ch = w*64 + nl*16 + lo]
            #pragma unroll
            for (int r = 0; r < 4; ++r) {
                const int p = mt * 16 + hi * 4 + r;
                const float2* ssrow = g_ssC + (size_t)(b * N_ + p) * HM_;
                #pragma unroll
                for (int nl = 0; nl < 4; ++nl) {
                    float2 ss = ssrow[w * 64 + nl * 16 + lo];
                    float ep = acc[nl][r];
                    float tx = rr[nl].x + ss.x;                 // (recv+send)/sqrt2
                    float E1 = __expf(2.0f * tx);
                    float th = fmaf(-2.0f, __builtin_amdgcn_rcpf(E1 + 1.0f), 1.0f);
                    float z  = rr[nl].y + ss.y;                 // (rn+sn)/sqrt2
                    float sg = __builtin_amdgcn_rcpf(1.0f + __expf(-z));
                    upd[nl] = fmaf(th * sg, ep, upd[nl]);
                }
            }
        }
    }

    // --- reduce over the 4 hi-groups (completes the sender sum)
    #pragma unroll
    for (int nl = 0; nl < 4; ++nl) {
        upd[nl] += __shfl_xor(upd[nl], 16);
        upd[nl] += __shfl_xor(upd[nl], 32);
    }

    // --- per-head LN (head0: nl 0,1 ; head1: nl 2,3 within this wave's 64 ch)
    float s0 = upd[0] + upd[1], q0 = upd[0]*upd[0] + upd[1]*upd[1];
    float s1 = upd[2] + upd[3], q1 = upd[2]*upd[2] + upd[3]*upd[3];
    #pragma unroll
    for (int k = 8; k >= 1; k >>= 1) {
        s0 += __shfl_xor(s0, k); q0 += __shfl_xor(q0, k);
        s1 += __shfl_xor(s1, k); q1 += __shfl_xor(q1, k);
    }
    float mu0 = s0 * (1.0f / M_), va0 = q0 * (1.0f / M_) - mu0 * mu0;
    float mu1 = s1 * (1.0f / M_), va1 = q1 * (1.0f / M_) - mu1 * mu1;
    float rs0 = rsqrtf(va0 + EPS_), rs1 = rsqrtf(va1 + EPS_);
    float val = upd[hi];
    float o = (hi < 2) ? (val - mu0) * rs0 : (val - mu1) * rs1;
    out[bn * HM_ + w * 64 + l] = o;
}

// ---------------------------------------------------------------------------
extern "C" void kernel_launch(void* const* d_in, const int* in_sizes, int n_in,
                              void* d_out, int out_size, void* d_ws, size_t ws_size,
                              hipStream_t stream) {
    const float* embeddings = (const float*)d_in[0];
    const float* edge_feat  = (const float*)d_in[1];
    const int*   mask_raw   = (const int*)d_in[2];
    const float* node_feat  = (const float*)d_in[3];
    const float* W_edge     = (const float*)d_in[4];
    const float* W_recv     = (const float*)d_in[5];
    const float* W_send     = (const float*)d_in[6];
    const float* W_recvn    = (const float*)d_in[7];
    const float* W_sendn    = (const float*)d_in[8];
    float* out = (float*)d_out;

    // workspace layout
    float2* g_ssC = (float2*)d_ws;                        // 4 MB
    float2* g_rr  = g_ssC + (size_t)BN_ * HM_;            // 4 MB
    unsigned long long* mask64 = (unsigned long long*)(g_rr + (size_t)BN_ * HM_); // 256 B
    int* cnt  = (int*)(mask64 + B_);                      // 128 B
    int* sidx = cnt + B_;                                 // 8 KB

    node_k<<<2 * B_, 256, 0, stream>>>(embeddings, node_feat, mask_raw,
                                       W_recv, W_send, W_recvn, W_sendn,
                                       g_rr, g_ssC, cnt, sidx, mask64);
    edge_agg<<<BN_, 256, 0, stream>>>(edge_feat, mask64, cnt, sidx, W_edge,
                                      g_rr, g_ssC, out);
}